// Round 10
// baseline (158.866 us; speedup 1.0000x reference)
//
#include <hip/hip_runtime.h>
#include <hip/hip_fp16.h>

#define IN_F   4096
#define OUT_F  8192
#define M_ROWS 256

// R10 = R9 with the cvt_pkrtz type fixed (__fp16 ext vector, matching the
// builtin's return type; unpack via bit-reinterpret, no __fp16 arithmetic).
// R9 theory under test: (1) controlled-depth pipeline: B depth-4 / A depth-2
// with NAMED buffers, 4 explicit phases, #pragma unroll 1 (R8's full unroll
// caused 30MB scratch spill -> 98us). (2) fp16 fragment-linear partials:
// 64+64MB -> 32+32MB partial traffic, coalesced dwordx4 both sides.
#define SPLITK  8
#define KSTEPS  (IN_F / 32)        // 128 ksteps of K=32 total
#define NIT     (KSTEPS / SPLITK)  // 16 ksteps per block
#define NSTRIPS (OUT_F / 64)       // 128 n-strips of 64
#define NTHR_TOT (16 * 2 * 512)    // gemm grid threads per z = 16384

typedef __attribute__((ext_vector_type(8))) short  short8;   // 8 bf16
typedef __attribute__((ext_vector_type(4))) float  float4v;  // 4 fp32 acc
typedef __attribute__((ext_vector_type(2))) __fp16 f16x2;    // cvt_pkrtz ret

union pk8 { uint4 u; short8 s; };
union hbits { __half h; unsigned short u; };
union f16pk { f16x2 h; unsigned int u; };

// pack two fp32 into bf16x2 (truncation): [bf16(lo) | bf16(hi)<<16]
__device__ inline unsigned int pack_bf16(float lo, float hi) {
    return __builtin_amdgcn_perm(__float_as_uint(hi), __float_as_uint(lo), 0x07060302u);
}

__device__ inline float h2f_bits(unsigned int b) {
    hbits t; t.u = (unsigned short)b;
    return __half2float(t.h);
}

// two fp32 -> packed fp16x2 (RTZ)
__device__ inline unsigned int pkh2(float a, float b) {
    f16pk c; c.h = __builtin_amdgcn_cvt_pkrtz(a, b);
    return c.u;
}

// packed fp16x2 -> two fp32 (bit-reinterpret each half)
__device__ inline float2 uph2(unsigned int u) {
    return make_float2(h2f_bits(u & 0xFFFFu), h2f_bits(u >> 16));
}

// out[m][n] = bias[n]  (fallback path only: atomics land on top)
__global__ void init_out_kernel(const float* __restrict__ bias, float* __restrict__ out) {
    int i = blockIdx.x * blockDim.x + threadIdx.x;
    if (i < (M_ROWS * OUT_F) / 4) {
        float4 b = ((const float4*)bias)[i & (OUT_F / 4 - 1)];
        ((float4*)out)[i] = b;
    }
}

// standalone cvt (fallback paths)
__global__ void cvt_x_kernel(const float* __restrict__ x, uint4* __restrict__ xb) {
    const int tid = blockIdx.x * blockDim.x + threadIdx.x;
    if (tid >= (M_ROWS * IN_F) / 8) return;
    const int lane = tid & 63;
    const int mf   = (tid >> 6) & 15;
    const int ks   = tid >> 10;
    const int m    = mf * 16 + (lane & 15);
    const int k    = ks * 32 + (lane >> 4) * 8;
    const float* p = x + m * IN_F + k;
    float4 v0 = ((const float4*)p)[0], v1 = ((const float4*)p)[1];
    uint4 o;
    o.x = pack_bf16(v0.x, v0.y); o.y = pack_bf16(v0.z, v0.w);
    o.z = pack_bf16(v1.x, v1.y); o.w = pack_bf16(v1.z, v1.w);
    xb[tid] = o;
}

// ---- repack v2 (LDS-transpose, verified R6-R8) + fused cvt_x ----
__global__ __launch_bounds__(256) void prep_kernel(
    const int* __restrict__ wq, const void* __restrict__ wnorm,
    uint4* __restrict__ bs, const float* __restrict__ x,
    uint4* __restrict__ xb) {
    __shared__ unsigned int qlds[64 * 64];   // 16 KB: [row][dword]
    __shared__ unsigned int nlds[64 * 32];   // 8 KB:  [row][dword]

    const int t = threadIdx.x;
    const int s = blockIdx.x;   // strip (or cvt slice)
    const int w = blockIdx.y;   // kwin | 4 = cvt

    if (w == 4) {
#pragma unroll
        for (int e = 0; e < 4; ++e) {
            const int tid = e * (NSTRIPS * 256) + s * 256 + t;
            const int lane = tid & 63;
            const int mf   = (tid >> 6) & 15;
            const int ks   = tid >> 10;
            const int m    = mf * 16 + (lane & 15);
            const int k    = ks * 32 + (lane >> 4) * 8;
            const float* p = x + (size_t)m * IN_F + k;
            float4 v0 = ((const float4*)p)[0], v1 = ((const float4*)p)[1];
            uint4 o;
            o.x = pack_bf16(v0.x, v0.y); o.y = pack_bf16(v0.z, v0.w);
            o.z = pack_bf16(v1.x, v1.y); o.w = pack_bf16(v1.z, v1.w);
            xb[tid] = o;
        }
        return;
    }

    const float cand0 = *(const float*)wnorm;
    const bool  nf32  = (cand0 > 1e-5f && cand0 < 0.1f);

    {
        const int p    = t & 63;
        const int rsub = t >> 6;
#pragma unroll
        for (int j = 0; j < 16; ++j) {
            const int row  = j * 4 + rsub;
            const int rowg = s * 64 + row;
            int4 d = *(const int4*)(wq + (size_t)rowg * (IN_F / 4) + w * 256 + p * 4);
            unsigned int t01   = __builtin_amdgcn_perm((unsigned)d.y, (unsigned)d.x, 0x00000400u);
            unsigned int t23   = __builtin_amdgcn_perm((unsigned)d.w, (unsigned)d.z, 0x00000400u);
            unsigned int bytes = __builtin_amdgcn_perm(t23, t01, 0x05040100u);
            const int chunk = (p >> 1) ^ (row & 31);
            qlds[row * 64 + ((chunk << 1) | (p & 1))] = bytes;
        }
    }
    {
        const int p    = t & 31;
        const int rsub = t >> 5;
#pragma unroll
        for (int j = 0; j < 8; ++j) {
            const int row  = j * 8 + rsub;
            const int rowg = s * 64 + row;
            unsigned int packed;
            if (nf32) {
                const float2 v = *(const float2*)((const float*)wnorm +
                                   (size_t)rowg * (IN_F / 16) + w * 64 + p * 2);
                hbits a, b; a.h = __float2half(v.x); b.h = __float2half(v.y);
                packed = (unsigned int)a.u | ((unsigned int)b.u << 16);
            } else {
                packed = *(const unsigned int*)((const unsigned short*)wnorm +
                           (size_t)rowg * (IN_F / 16) + w * 64 + p * 2);
            }
            nlds[row * 32 + (p ^ (row & 31))] = packed;
        }
    }
    __syncthreads();

    const int base = (s * KSTEPS + w * 32) * 64;
#pragma unroll
    for (int e = 0; e < 8; ++e) {
        const int id   = e * 256 + t;
        const int ks   = id >> 6;
        const int lane = id & 63;
        const int quad = lane >> 4;
        const int l15  = lane & 15;
        const int q2   = quad >> 1;
        const int hsel = quad & 1;
        unsigned int q16[4], n16[4];
#pragma unroll
        for (int j = 0; j < 4; ++j) {
            const int row = j * 16 + l15;
            const int cs  = ks ^ (row & 31);
            const unsigned int qv = qlds[row * 64 + ((cs << 1) | q2)];
            q16[j] = (qv >> (hsel * 16)) & 0xFFFFu;
            const unsigned int nv = nlds[row * 32 + cs];
            n16[j] = (nv >> (q2 * 16)) & 0xFFFFu;
        }
        uint4 r;
        r.x = q16[0] | (q16[1] << 16);
        r.y = q16[2] | (q16[3] << 16);
        r.z = n16[0] | (n16[1] << 16);
        r.w = n16[2] | (n16[3] << 16);
        bs[base + id] = r;
    }
}

// out = sum_z P16[z] + bias, using the same thread geometry as the gemm
// (grid (16,2) x 512). P16 layout: [z][slot 0..15][bt 0..16383] uint4,
// slot = j*2 + h, uint4 = {i=2h:(r0r1,r2r3), i=2h+1:(r0r1,r2r3)} fp16.
__global__ __launch_bounds__(512) void reduce_out_kernel(
    const uint4* __restrict__ P, const float* __restrict__ bias,
    float* __restrict__ out) {
    const int t    = threadIdx.x;
    const int wave = t >> 6;
    const int lane = t & 63;
    const int l15  = lane & 15;
    const int quad = lane >> 4;
    const int wm   = wave >> 2;
    const int wn   = wave & 3;
    const int s0   = blockIdx.x * 8 + wn * 2;
    const int m0   = blockIdx.y * 128 + wm * 64;
    const size_t bt = ((size_t)blockIdx.y * gridDim.x + blockIdx.x) * blockDim.x + t;

#pragma unroll
    for (int j = 0; j < 8; ++j) {
        const int col = s0 * 64 + (j >> 2) * 64 + (j & 3) * 16 + l15;
        const float bv = bias[col];
#pragma unroll
        for (int h = 0; h < 2; ++h) {
            float v[8] = {};
#pragma unroll
            for (int z = 0; z < SPLITK; ++z) {
                uint4 u = P[((size_t)z * 16 + (j * 2 + h)) * NTHR_TOT + bt];
                float2 p0 = uph2(u.x), p1 = uph2(u.y), p2 = uph2(u.z), p3 = uph2(u.w);
                v[0] += p0.x; v[1] += p0.y; v[2] += p1.x; v[3] += p1.y;
                v[4] += p2.x; v[5] += p2.y; v[6] += p3.x; v[7] += p3.y;
            }
            const int i0 = h * 2;
            const int rowA = m0 + i0 * 16 + quad * 4;
            const int rowB = m0 + (i0 + 1) * 16 + quad * 4;
#pragma unroll
            for (int r = 0; r < 4; ++r) {
                out[(size_t)(rowA + r) * OUT_F + col] = v[r] + bv;
                out[(size_t)(rowB + r) * OUT_F + col] = v[4 + r] + bv;
            }
        }
    }
}

// C partial[z] = X * W^T over this block's K range (fp16 frag-linear).
// 512 thr = 8 waves = 2m x 4n of 64m x 128n wave-tiles; BM=128, BN=512.
// Grid (16, 2, SPLITK=8) = 256 blocks. No LDS, no barriers.
// Pipeline: A depth-2, B depth-4, NAMED buffers, 4 explicit phases,
// #pragma unroll 1 (bounds live set; R8 lesson), clamped uniform prefetch.
template <bool XB, bool BS, bool PW>
__global__ __launch_bounds__(512, 2) void gemm2bit_kernel(
    const float* __restrict__ xf,     // !XB: fp32 x (frag-gathered)
    const uint4* __restrict__ xb,     // XB: frag-ordered bf16 ws
    const uint4* __restrict__ bs,     // BS: repacked B stream
    const int*   __restrict__ wq,     // !BS: raw packed weights
    const void*  __restrict__ wnorm,  // !BS: raw norms (fp32/fp16 detected)
    float*       __restrict__ out)    // PW: P16 base; !PW: out (atomics)
{
    const int t    = threadIdx.x;
    const int wave = t >> 6;
    const int lane = t & 63;
    const int l15  = lane & 15;
    const int quad = lane >> 4;
    const int wm   = wave >> 2;            // 0..1
    const int wn   = wave & 3;             // 0..3

    const int s0   = blockIdx.x * 8 + wn * 2;        // first of 2 n-strips
    const int m0   = blockIdx.y * 128 + wm * 64;     // wave m base
    const int mb   = blockIdx.y * 8 + wm * 4;        // m-frag base
    const int ks0  = blockIdx.z * NIT;               // first kstep

    bool nf32 = false;
    if (!BS) {
        const float cand0 = *(const float*)wnorm;
        nf32 = (cand0 > 1e-5f && cand0 < 0.1f);
    }

    float4v acc[4][8] = {};

    auto kcl = [&](int k) { return k < KSTEPS ? k : KSTEPS - 1; };  // uniform

    auto loadA = [&](uint4 (&a)[4], int ks) {
        if (XB) {
#pragma unroll
            for (int i = 0; i < 4; ++i)
                a[i] = xb[(size_t)(ks * 16 + mb + i) * 64 + lane];
        } else {
#pragma unroll
            for (int i = 0; i < 4; ++i) {
                const float* p = xf + (size_t)(m0 + i * 16 + l15) * IN_F + ks * 32 + quad * 8;
                float4 v0 = ((const float4*)p)[0], v1 = ((const float4*)p)[1];
                a[i].x = pack_bf16(v0.x, v0.y); a[i].y = pack_bf16(v0.z, v0.w);
                a[i].z = pack_bf16(v1.x, v1.y); a[i].w = pack_bf16(v1.z, v1.w);
            }
        }
    };

    auto loadB1 = [&](uint4& bv, int strip, int ks) {
        if (BS) {
            bv = bs[(size_t)(strip * KSTEPS + ks) * 64 + lane];
        } else {
            unsigned int q16[4], n16[4];
#pragma unroll
            for (int j = 0; j < 4; ++j) {
                const int n = strip * 64 + j * 16 + l15;
                const int2 q = *(const int2*)((const char*)wq +
                                  (size_t)n * (IN_F / 4) * 4 + (size_t)ks * 32 + quad * 8);
                q16[j] = (unsigned int)((q.x & 0xFF) | ((q.y & 0xFF) << 8));
                const int g = n * (IN_F / 16) + ks * 2 + (quad >> 1);
                if (nf32) {
                    hbits h; h.h = __float2half(((const float*)wnorm)[g]);
                    n16[j] = h.u;
                } else {
                    n16[j] = ((const unsigned short*)wnorm)[g];
                }
            }
            bv.x = q16[0] | (q16[1] << 16);
            bv.y = q16[2] | (q16[3] << 16);
            bv.z = n16[0] | (n16[1] << 16);
            bv.w = n16[2] | (n16[3] << 16);
        }
    };

    auto loadBpair = [&](uint4 (&b2)[2], int ks) {
        loadB1(b2[0], s0, ks);
        loadB1(b2[1], s0 + 1, ks);
    };

    auto procRec = [&](uint4 (&a)[4], const uint4& bv, int jb) {
        const unsigned int qd[2] = { bv.x, bv.y };
        const unsigned int nd[2] = { bv.z, bv.w };
#pragma unroll
        for (int j = 0; j < 4; ++j) {
            const unsigned int qn = (qd[j >> 1] >> ((j & 1) * 16)) & 0xFFFFu;
            const float nC = h2f_bits((nd[j >> 1] >> ((j & 1) * 16)) & 0xFFFFu);
            const float s  = nC * (2.0f / 3.0f);
            float f[8];
#pragma unroll
            for (int i = 0; i < 4; ++i)
                f[i]     = fmaf((float)((qn >> (2 * i)) & 3), s, -nC);
#pragma unroll
            for (int i = 0; i < 4; ++i)
                f[4 + i] = fmaf((float)((qn >> (8 + 2 * i)) & 3), s, -nC);
            pk8 b;
            b.u.x = pack_bf16(f[0], f[1]); b.u.y = pack_bf16(f[2], f[3]);
            b.u.z = pack_bf16(f[4], f[5]); b.u.w = pack_bf16(f[6], f[7]);
#pragma unroll
            for (int i = 0; i < 4; ++i) {
                pk8 av; av.u = a[i];
                acc[i][jb + j] = __builtin_amdgcn_mfma_f32_16x16x32_bf16(av.s, b.s, acc[i][jb + j], 0, 0, 0);
            }
        }
    };

    auto procPair = [&](uint4 (&a)[4], uint4 (&b2)[2]) {
        procRec(a, b2[0], 0);
        procRec(a, b2[1], 4);
    };

    // ---- prologue ----
    uint4 a0[4], a1[4], bb0[2], bb1[2], bb2[2], bb3[2];
    loadA(a0, ks0);      loadA(a1, ks0 + 1);
    loadBpair(bb0, ks0);     loadBpair(bb1, ks0 + 1);
    loadBpair(bb2, ks0 + 2); loadBpair(bb3, ks0 + 3);

    // ---- main loop: 4 ksteps/iter, named buffers, bounded live set ----
#pragma unroll 1
    for (int it = 0; it < NIT; it += 4) {
        procPair(a0, bb0);
        loadA(a0, kcl(ks0 + it + 2));  loadBpair(bb0, kcl(ks0 + it + 4));
        procPair(a1, bb1);
        loadA(a1, kcl(ks0 + it + 3));  loadBpair(bb1, kcl(ks0 + it + 5));
        procPair(a0, bb2);
        loadA(a0, kcl(ks0 + it + 4));  loadBpair(bb2, kcl(ks0 + it + 6));
        procPair(a1, bb3);
        loadA(a1, kcl(ks0 + it + 5));  loadBpair(bb3, kcl(ks0 + it + 7));
    }

    // ---- epilogue ----
    if (PW) {
        // fp16 frag-linear partials: [z][slot][bt], fully coalesced
        uint4* P = reinterpret_cast<uint4*>(out);
        const size_t bt = ((size_t)blockIdx.y * gridDim.x + blockIdx.x) * blockDim.x + t;
        const size_t zb = (size_t)blockIdx.z * 16 * NTHR_TOT;
#pragma unroll
        for (int j = 0; j < 8; ++j) {
#pragma unroll
            for (int h = 0; h < 2; ++h) {
                const int i0 = h * 2, i1 = h * 2 + 1;
                uint4 u;
                u.x = pkh2(acc[i0][j][0], acc[i0][j][1]);
                u.y = pkh2(acc[i0][j][2], acc[i0][j][3]);
                u.z = pkh2(acc[i1][j][0], acc[i1][j][1]);
                u.w = pkh2(acc[i1][j][2], acc[i1][j][3]);
                P[zb + (size_t)(j * 2 + h) * NTHR_TOT + bt] = u;
            }
        }
    } else {
        // atomic fallback: D[row=quad*4+r][col=lane&15] mapping (verified)
#pragma unroll
        for (int j = 0; j < 8; ++j) {
            const int col = s0 * 64 + (j >> 2) * 64 + (j & 3) * 16 + l15;
#pragma unroll
            for (int i = 0; i < 4; ++i) {
                const int row0 = m0 + i * 16 + quad * 4;
#pragma unroll
                for (int r = 0; r < 4; ++r)
                    atomicAdd(&out[(size_t)(row0 + r) * OUT_F + col], acc[i][j][r]);
            }
        }
    }
}

extern "C" void kernel_launch(void* const* d_in, const int* in_sizes, int n_in,
                              void* d_out, int out_size, void* d_ws, size_t ws_size,
                              hipStream_t stream) {
    const float* x    = (const float*)d_in[0];
    const int*   wq   = (const int*)d_in[1];
    const void*  wn   = (const void*)d_in[2];
    const float* bias = (const float*)d_in[3];
    float*       out  = (float*)d_out;

    const size_t xb_bytes = (size_t)M_ROWS * IN_F * 2;            // 2 MB
    const size_t bs_bytes = (size_t)NSTRIPS * KSTEPS * 64 * 16;   // 16 MB
    const size_t p16_bytes = (size_t)SPLITK * M_ROWS * OUT_F * 2; // 32 MB

    dim3 grid(OUT_F / 512, M_ROWS / 128, SPLITK);  // (16, 2, 8) = 256 blocks

    if (ws_size >= xb_bytes + bs_bytes + p16_bytes) {
        // full path: fused prep + gemm (fp16 frag partials) + reduce
        uint4* xbv = (uint4*)d_ws;
        uint4* bsw = (uint4*)((char*)d_ws + xb_bytes);
        float* p16 = (float*)((char*)d_ws + xb_bytes + bs_bytes);
        prep_kernel<<<dim3(NSTRIPS, 5), 256, 0, stream>>>(wq, wn, bsw, x, xbv);
        gemm2bit_kernel<true, true, true><<<grid, 512, 0, stream>>>(
            nullptr, xbv, bsw, wq, wn, p16);
        reduce_out_kernel<<<dim3(OUT_F / 512, M_ROWS / 128), 512, 0, stream>>>(
            (const uint4*)p16, bias, out);
    } else if (ws_size >= xb_bytes + bs_bytes) {
        uint4* xbv = (uint4*)d_ws;
        uint4* bsw = (uint4*)((char*)d_ws + xb_bytes);
        init_out_kernel<<<dim3((M_ROWS * OUT_F / 4) / 256), 256, 0, stream>>>(bias, out);
        prep_kernel<<<dim3(NSTRIPS, 5), 256, 0, stream>>>(wq, wn, bsw, x, xbv);
        gemm2bit_kernel<true, true, false><<<grid, 512, 0, stream>>>(
            nullptr, xbv, bsw, wq, wn, out);
    } else if (ws_size >= xb_bytes) {
        uint4* xbv = (uint4*)d_ws;
        init_out_kernel<<<dim3((M_ROWS * OUT_F / 4) / 256), 256, 0, stream>>>(bias, out);
        cvt_x_kernel<<<dim3((M_ROWS * IN_F / 8) / 256), 256, 0, stream>>>(x, xbv);
        gemm2bit_kernel<true, false, false><<<grid, 512, 0, stream>>>(
            nullptr, xbv, nullptr, wq, wn, out);
    } else {
        init_out_kernel<<<dim3((M_ROWS * OUT_F / 4) / 256), 256, 0, stream>>>(bias, out);
        gemm2bit_kernel<false, false, false><<<grid, 512, 0, stream>>>(
            x, nullptr, nullptr, wq, wn, out);
    }
}